// Round 1
// baseline (1334.772 us; speedup 1.0000x reference)
//
#include <hip/hip_runtime.h>
#include <math.h>

#define Bb   2048
#define Mm   2048
#define Hh   64
#define Dd   64
#define Vv   128
#define Gg   32
#define NIT  (Mm / 16)

static __device__ __forceinline__ float4 ld4(const float* p) {
    return *reinterpret_cast<const float4*>(p);
}

__global__ __launch_bounds__(256, 8)
void retriever_kernel(const float* __restrict__ query,
                      const float* __restrict__ memory,
                      const float* __restrict__ Wq,  const float* __restrict__ bq,
                      const float* __restrict__ Wo,  const float* __restrict__ bo,
                      const float* __restrict__ Wg1, const float* __restrict__ bg1,
                      const float* __restrict__ Wg2, const float* __restrict__ bg2,
                      const float* __restrict__ null_vec,
                      const float* __restrict__ Wc,  const float* __restrict__ bc,
                      float* __restrict__ logits_out,
                      float* __restrict__ gate_out)
{
    constexpr float L2E = 1.44269504088896340736f;

    __shared__ float q_lds[Hh];
    __shared__ float qp_lds[Dd];
    __shared__ float red_max[16];
    __shared__ float red_den[16];
    __shared__ float red_acc[16][Dd];
    __shared__ float r_lds[Dd];
    __shared__ float out_lds[Hh];
    __shared__ float M_lds;
    __shared__ float gate_lds;

    const int b    = blockIdx.x;
    const int t    = threadIdx.x;
    const int wave = t >> 6;
    const int lane = t & 63;
    const int grp  = lane >> 4;      // 16-lane group within wave
    const int l    = lane & 15;      // lane within group
    const int gidx = (wave << 2) | grp;   // 0..15: partial-state index

    // ---- stage query row ----
    if (t < Hh) q_lds[t] = query[(size_t)b * Hh + t];
    __syncthreads();

    // ---- q_proj = (query @ Wq + bq) * (1/sqrt(D)) ----
    if (t < Dd) {
        float a = bq[t];
        #pragma unroll 8
        for (int h = 0; h < Hh; ++h)
            a = fmaf(q_lds[h], Wq[h * Dd + t], a);
        qp_lds[t] = a * 0.125f;   // fold 1/sqrt(64)
    }
    __syncthreads();

    const float4 qp = ld4(&qp_lds[4 * l]);

    // ---- single pass over memory[b]: online softmax + weighted accumulate ----
    const float* memb = memory + (size_t)b * Mm * Dd;
    const float* p0   = memb + (size_t)gidx * Dd + 4 * l;

    float  mx  = -1e30f;
    float  den = 0.f;
    float4 acc = make_float4(0.f, 0.f, 0.f, 0.f);

    float4 cur = ld4(p0);
    for (int it = 0; it < NIT; ++it) {
        const int itn = (it + 1 < NIT) ? it + 1 : it;      // unconditional prefetch
        float4 nxt = ld4(p0 + (size_t)itn * 16 * Dd);

        // dot(q_proj, mem_row) — partial over this lane's 4 elems, reduce over 16 lanes
        float s = qp.x * cur.x + qp.y * cur.y + qp.z * cur.z + qp.w * cur.w;
        s += __shfl_xor(s, 1);
        s += __shfl_xor(s, 2);
        s += __shfl_xor(s, 4);
        s += __shfl_xor(s, 8);

        // branchless online-softmax update
        const float mxn = fmaxf(mx, s);
        const float w   = exp2f((s  - mxn) * L2E);
        const float c   = exp2f((mx - mxn) * L2E);
        mx  = mxn;
        den = den * c + w;
        acc.x = acc.x * c + w * cur.x;
        acc.y = acc.y * c + w * cur.y;
        acc.z = acc.z * c + w * cur.z;
        acc.w = acc.w * c + w * cur.w;

        cur = nxt;
    }

    // ---- write 16 partial states to LDS ----
    if (l == 0) { red_max[gidx] = mx; red_den[gidx] = den; }
    *reinterpret_cast<float4*>(&red_acc[gidx][4 * l]) = acc;
    __syncthreads();

    // ---- combine partials; retrieved = acc_total / den_total ----
    if (t < Dd) {
        float Mx = red_max[0];
        #pragma unroll
        for (int g = 1; g < 16; ++g) Mx = fmaxf(Mx, red_max[g]);
        float dt = 0.f, a = 0.f;
        #pragma unroll
        for (int g = 0; g < 16; ++g) {
            const float sc = exp2f((red_max[g] - Mx) * L2E);
            dt = fmaf(red_den[g],    sc, dt);
            a  = fmaf(red_acc[g][t], sc, a);
        }
        r_lds[t] = a / dt;
        if (t == 0) M_lds = Mx;
    }
    __syncthreads();

    // ---- wave 0: retrieved_h = retrieved @ Wo + bo ; wave 1 lanes 0-31: gate MLP ----
    float rh = 0.f;
    if (t < Hh) {
        rh = bo[t];
        #pragma unroll 8
        for (int d = 0; d < Dd; ++d)
            rh = fmaf(r_lds[d], Wo[d * Hh + t], rh);
    } else if (t < 96) {
        const int g = t - 64;
        float a = fmaf(M_lds, Wg1[Hh * Gg + g], bg1[g]);
        #pragma unroll 8
        for (int i = 0; i < Hh; ++i)
            a = fmaf(q_lds[i], Wg1[i * Gg + g], a);
        a  = fmaxf(a, 0.f);     // relu
        rh = a * Wg2[g];        // partial of hidden @ Wg2
    }

    if (wave == 1) {
        // reduce gate partial across lanes 0..31 (lanes 32..63 hold 0)
        float gs = rh;
        gs += __shfl_xor(gs, 1);
        gs += __shfl_xor(gs, 2);
        gs += __shfl_xor(gs, 4);
        gs += __shfl_xor(gs, 8);
        gs += __shfl_xor(gs, 16);
        if (lane == 0) {
            const float x = gs + bg2[0];
            const float gate = 1.f / (1.f + exp2f(-x * L2E));
            gate_lds = gate;
            gate_out[b] = gate;
        }
    }
    __syncthreads();

    // ---- gated output ----
    if (t < Hh) {
        const float gate = gate_lds;
        out_lds[t] = gate * rh + (1.f - gate) * null_vec[t];
    }
    __syncthreads();

    // ---- logits = out @ Wc + bc ----
    if (t < Vv) {
        float lg = bc[t];
        #pragma unroll 8
        for (int h = 0; h < Hh; ++h)
            lg = fmaf(out_lds[h], Wc[h * Vv + t], lg);
        logits_out[(size_t)b * Vv + t] = lg;
    }
}

extern "C" void kernel_launch(void* const* d_in, const int* in_sizes, int n_in,
                              void* d_out, int out_size, void* d_ws, size_t ws_size,
                              hipStream_t stream) {
    const float* query    = (const float*)d_in[0];
    const float* memory   = (const float*)d_in[1];
    const float* Wq       = (const float*)d_in[2];
    const float* bq       = (const float*)d_in[3];
    const float* Wo       = (const float*)d_in[4];
    const float* bo       = (const float*)d_in[5];
    const float* Wg1      = (const float*)d_in[6];
    const float* bg1      = (const float*)d_in[7];
    const float* Wg2      = (const float*)d_in[8];
    const float* bg2      = (const float*)d_in[9];
    const float* null_vec = (const float*)d_in[10];
    const float* Wc       = (const float*)d_in[11];
    const float* bc       = (const float*)d_in[12];

    float* logits = (float*)d_out;                       // (B, V) flat
    float* gate   = (float*)d_out + (size_t)Bb * Vv;     // (B,)

    retriever_kernel<<<Bb, 256, 0, stream>>>(
        query, memory, Wq, bq, Wo, bo, Wg1, bg1, Wg2, bg2,
        null_vec, Wc, bc, logits, gate);
}